// Round 1
// 4380.334 us; speedup vs baseline: 1.2437x; 1.2437x over previous
//
#include <hip/hip_runtime.h>

#define NUM_ITERS 15
#define BB 2
#define NN 2048
#define QQ 256
#define CHUNKS 16          // colsum n-chunks of 128 rows

// ---------------------------------------------------------------------------
// Numerical contract (matches numpy-fp32 golden; verified absmax 0.00195 in
// R8/R9 — LOAD-BEARING, do not relax):
//  - no FMA contraction (pragma clang fp contract(off))
//  - GEMM per output element: single fp32 accumulator, strictly ascending k,
//    round(mul) then round(add), final true division by max(sum,1)
//  - row reductions over q=256: numpy pairwise tree (8-acc blocks of 128,
//    fixed combine), association order replicated exactly
//  - colsum: ascending-n in 16 chunks, combined ascending
// ---------------------------------------------------------------------------

__global__ __launch_bounds__(256) void colsum_part(
    const float* __restrict__ adj, const float* __restrict__ act,
    float* __restrict__ pe0, float* __restrict__ pi0,
    float* __restrict__ pe1, float* __restrict__ pi1)
{
#pragma clang fp contract(off)
    const int b = (int)blockIdx.z;
    const int c = (int)blockIdx.y;
    const int m = (int)blockIdx.x * 256 + (int)threadIdx.x;
    const float* src = adj + (size_t)b * NN * NN;
    const float* ab  = act + (size_t)b * NN;
    float se0 = 0.0f, si0 = 0.0f, se1 = 0.0f, si1 = 0.0f;
    const int n0 = c * (NN / CHUNKS);
    for (int n = n0; n < n0 + NN / CHUNKS; ++n) {
        float x = src[(size_t)n * NN + m];
        float e = (x > 0.5f) ? x : 0.0f;
        float v = 1.0f - x;
        float iv = (v > 0.5f) ? v : 0.0f;
        float av = ab[n];
        se1 = se1 + e;
        si1 = si1 + iv;
        se0 = se0 + e * av;
        si0 = si0 + iv * av;
    }
    size_t o = ((size_t)c * BB + b) * NN + m;
    pe0[o] = se0; pi0[o] = si0; pe1[o] = se1; pi1[o] = si1;
}

__global__ __launch_bounds__(256) void colsum_combine(
    const float* __restrict__ pe0, const float* __restrict__ pi0,
    const float* __restrict__ pe1, const float* __restrict__ pi1,
    float* __restrict__ se0, float* __restrict__ si0,
    float* __restrict__ se1, float* __restrict__ si1)
{
#pragma clang fp contract(off)
    const int i = (int)blockIdx.x * 256 + (int)threadIdx.x;   // 0..BB*NN-1
    float a = 0.0f, bb = 0.0f, cc = 0.0f, dd = 0.0f;
    for (int c = 0; c < CHUNKS; ++c) {
        size_t o = (size_t)c * (BB * NN) + i;
        a  = a  + pe0[o];
        bb = bb + pi0[o];
        cc = cc + pe1[o];
        dd = dd + pi1[o];
    }
    se0[i] = a; si0[i] = bb; se1[i] = cc; si1[i] = dd;
}

// ---------------------------------------------------------------------------
// Fused thresholded GEMM, np-fp32-exact per-element chain:
//   C[m][q] = sum_k (thr(adj[k][m]) * act[k]) * hsrc[k][q]   (ascending k)
//   mode 0: dst = h_old + C/max(sum,1);  mode 1: dst = C/max(sum,1)
//
// v2 (this round): tile M=64 x Q=64, BK=64, 256 threads, 4x4 microtile.
//  - LDS as float4 arrays -> ds_read_b128 / ds_write_b128 (LDS floats per
//    MAC 1.0 -> 0.5; previous 2x2 kernel was LDS-read-throughput-bound).
//  - register prefetch of next K-tile (global loads issued before compute,
//    written to LDS after the read barrier) to hide HBM/L2 latency at the
//    resulting 1 block/CU occupancy (grid = 256 blocks exactly).
//  - per-element arithmetic chain (ascending k, mul then add, contract off,
//    true division) is bit-identical to the previous passing kernel.
// ---------------------------------------------------------------------------
__global__ __launch_bounds__(256, 1) void gemm_fused(
    const float* __restrict__ adj,
    const float* __restrict__ hsrc,
    const float* act,
    const float* __restrict__ sums,
    const float* h_old,
    float* __restrict__ dst,
    int mode)
{
#pragma clang fp contract(off)
    __shared__ float4 Ws[64][17];   // 64 k-rows x 16 float4 m-cols (+1 pad)
    __shared__ float4 Hs[64][17];   // 64 k-rows x 16 float4 q-cols (+1 pad)

    const int b  = (int)blockIdx.z;
    const int m0 = (int)blockIdx.x * 64;
    const int q0 = (int)blockIdx.y * 64;
    const int tid = (int)threadIdx.x;
    const int tm  = tid & 15;      // m-group: rows m0 + tm*4 .. +3
    const int tq  = tid >> 4;      // q-group: cols q0 + tq*4 .. +3

    const float* adjb = adj + (size_t)b * NN * NN;
    const float* hb   = hsrc + (size_t)b * NN * QQ;
    const float* ab   = (act != 0) ? (act + (size_t)b * NN) : (const float*)0;

    float acc[4][4];
    #pragma unroll
    for (int i = 0; i < 4; ++i)
        #pragma unroll
        for (int j = 0; j < 4; ++j)
            acc[i][j] = 0.0f;

    float4 wreg[4], hreg[4];

    // issue global loads for K-tile starting at kbase into regs
    auto stage_load = [&](int kbase) {
#pragma clang fp contract(off)
        #pragma unroll
        for (int j = 0; j < 4; ++j) {
            int idx = tid + j * 256;           // 0..1023
            int kk  = idx >> 4;                // 0..63
            int seg = idx & 15;                // 0..15 (float4 col)
            wreg[j] = *(const float4*)(adjb + (size_t)(kbase + kk) * NN + m0 + seg * 4);
            hreg[j] = *(const float4*)(hb   + (size_t)(kbase + kk) * QQ + q0 + seg * 4);
        }
    };

    // threshold + write regs -> LDS (kbase only needed for act indexing)
    auto stage_store = [&](int kbase) {
#pragma clang fp contract(off)
        #pragma unroll
        for (int j = 0; j < 4; ++j) {
            int idx = tid + j * 256;
            int kk  = idx >> 4;
            int seg = idx & 15;
            float4 x = wreg[j];
            float4 w;
            if (mode == 0) {
                w.x = (x.x > 0.5f) ? x.x : 0.0f;
                w.y = (x.y > 0.5f) ? x.y : 0.0f;
                w.z = (x.z > 0.5f) ? x.z : 0.0f;
                w.w = (x.w > 0.5f) ? x.w : 0.0f;
            } else {
                float vx = 1.0f - x.x; w.x = (vx > 0.5f) ? vx : 0.0f;
                float vy = 1.0f - x.y; w.y = (vy > 0.5f) ? vy : 0.0f;
                float vz = 1.0f - x.z; w.z = (vz > 0.5f) ? vz : 0.0f;
                float vw = 1.0f - x.w; w.w = (vw > 0.5f) ? vw : 0.0f;
            }
            if (ab != 0) {
                float av = ab[kbase + kk];
                w.x = w.x * av; w.y = w.y * av; w.z = w.z * av; w.w = w.w * av;
            }
            Ws[kk][seg] = w;
            Hs[kk][seg] = hreg[j];
        }
    };

    // prologue: tile 0 into LDS
    stage_load(0);
    stage_store(0);
    __syncthreads();

    for (int k0 = 0; k0 < NN; k0 += 64) {
        const int knext = k0 + 64;
        if (knext < NN) stage_load(knext);     // overlap with compute below

        #pragma unroll
        for (int kk = 0; kk < 64; ++kk) {
            float4 a4 = Ws[kk][tm];
            float4 b4 = Hs[kk][tq];
            float va[4] = {a4.x, a4.y, a4.z, a4.w};
            float vb[4] = {b4.x, b4.y, b4.z, b4.w};
            #pragma unroll
            for (int i = 0; i < 4; ++i)
                #pragma unroll
                for (int j = 0; j < 4; ++j)
                    acc[i][j] = acc[i][j] + va[i] * vb[j];
        }
        __syncthreads();                       // all waves done reading LDS
        if (knext < NN) {
            stage_store(knext);                // implicit vmcnt wait here
            __syncthreads();                   // stores visible before reads
        }
    }

    // epilogue: true division, optional h_old add, float4 stores
    #pragma unroll
    for (int i = 0; i < 4; ++i) {
        int row = m0 + tm * 4 + i;
        float s = sums[b * NN + row];
        if (s < 1.0f) s = 1.0f;
        float v0 = acc[i][0] / s;
        float v1 = acc[i][1] / s;
        float v2 = acc[i][2] / s;
        float v3 = acc[i][3] / s;
        size_t g = ((size_t)b * NN + row) * QQ + q0 + tq * 4;
        float4 o;
        if (mode == 0) {
            float4 ho = *(const float4*)(h_old + g);
            o.x = ho.x + v0; o.y = ho.y + v1; o.z = ho.z + v2; o.w = ho.w + v3;
        } else {
            o.x = v0; o.y = v1; o.z = v2; o.w = v3;
        }
        *(float4*)(dst + g) = o;
    }
}

// ---------------------------------------------------------------------------
// Projection + relu + L2-normalize, np-fp32-exact, in place on h_io.
// Pairwise trees parallelized with IDENTICAL association order.
// Block = one row m (256 threads). Grid (NN, BB).
// ---------------------------------------------------------------------------
__global__ __launch_bounds__(256) void project_kernel(
    float* h_io, const float* __restrict__ ieff)
{
#pragma clang fp contract(off)
    __shared__ float sp[256];
    __shared__ float sq[256];
    __shared__ float rs[32];
    __shared__ float sc[2];
    const int b = (int)blockIdx.y;
    const int m = (int)blockIdx.x;
    const int t = (int)threadIdx.x;

    size_t gi = ((size_t)b * NN + m) * QQ + t;
    float hv = h_io[gi];
    float ie = ieff[gi];

    sp[t] = hv * ie;
    sq[t] = ie * ie;
    __syncthreads();
    if (t < 32) {
        const float* a = (t < 16) ? sp : sq;
        int j = t & 7;
        int base = (t & 8) ? 128 : 0;
        float r = a[base + j];
        for (int i = 8; i < 128; i += 8) r = r + a[base + i + j];
        rs[t] = r;
    }
    __syncthreads();
    if (t == 0) {
        float d0 = ((rs[0] + rs[1]) + (rs[2] + rs[3])) + ((rs[4] + rs[5]) + (rs[6] + rs[7]));
        float d1 = ((rs[8] + rs[9]) + (rs[10] + rs[11])) + ((rs[12] + rs[13]) + (rs[14] + rs[15]));
        float dot = d0 + d1;
        float u0 = ((rs[16] + rs[17]) + (rs[18] + rs[19])) + ((rs[20] + rs[21]) + (rs[22] + rs[23]));
        float u1 = ((rs[24] + rs[25]) + (rs[26] + rs[27])) + ((rs[28] + rs[29]) + (rs[30] + rs[31]));
        float un = u0 + u1;
        sc[0] = dot / (un + 1e-12f);
    }
    __syncthreads();
    float c = sc[0];
    float tmp = c * ie;
    float h2 = hv - tmp;
    float r = (h2 > 0.0f) ? h2 : 0.0f;
    sp[t] = r * r;
    __syncthreads();
    if (t < 16) {
        int j = t & 7;
        int base = (t & 8) ? 128 : 0;
        float rr = sp[base + j];
        for (int i = 8; i < 128; i += 8) rr = rr + sp[base + i + j];
        rs[t] = rr;
    }
    __syncthreads();
    if (t == 0) {
        float n0 = ((rs[0] + rs[1]) + (rs[2] + rs[3])) + ((rs[4] + rs[5]) + (rs[6] + rs[7]));
        float n1 = ((rs[8] + rs[9]) + (rs[10] + rs[11])) + ((rs[12] + rs[13]) + (rs[14] + rs[15]));
        float nn = n0 + n1;
        float den = (float)sqrt((double)nn);
        if (den < 1e-8f) den = 1e-8f;
        sc[1] = den;
    }
    __syncthreads();
    h_io[gi] = r / sc[1];
}

// ---------------------------------------------------------------------------
extern "C" void kernel_launch(void* const* d_in, const int* in_sizes, int n_in,
                              void* d_out, int out_size, void* d_ws, size_t ws_size,
                              hipStream_t stream)
{
    const float* h0     = 0;
    const float* adj    = 0;
    const float* act_in = 0;
    for (int i = 0; i < n_in; ++i) {
        if (in_sizes[i] == BB * NN * QQ)      h0     = (const float*)d_in[i];
        else if (in_sizes[i] == BB * NN * NN) adj    = (const float*)d_in[i];
        else if (in_sizes[i] == BB * NN)      act_in = (const float*)d_in[i];
    }
    float* out = (float*)d_out;

    char* ws = (char*)d_ws;
    size_t off = 0;
    float* ieff = (float*)(ws + off); off += (size_t)BB * NN * QQ * 4;      // 4 MB
    float* pe0 = (float*)(ws + off); off += (size_t)CHUNKS * BB * NN * 4;   // 256 KB
    float* pi0 = (float*)(ws + off); off += (size_t)CHUNKS * BB * NN * 4;
    float* pe1 = (float*)(ws + off); off += (size_t)CHUNKS * BB * NN * 4;
    float* pi1 = (float*)(ws + off); off += (size_t)CHUNKS * BB * NN * 4;
    float* sum_e0 = (float*)(ws + off); off += (size_t)BB * NN * 4;
    float* sum_i0 = (float*)(ws + off); off += (size_t)BB * NN * 4;
    float* sum_e1 = (float*)(ws + off); off += (size_t)BB * NN * 4;
    float* sum_i1 = (float*)(ws + off); off += (size_t)BB * NN * 4;

    const size_t slice_sz = (size_t)BB * NN * QQ;

    colsum_part<<<dim3(NN / 256, CHUNKS, BB), 256, 0, stream>>>(
        adj, act_in, pe0, pi0, pe1, pi1);
    colsum_combine<<<dim3(BB * NN / 256), 256, 0, stream>>>(
        pe0, pi0, pe1, pi1, sum_e0, sum_i0, sum_e1, sum_i1);

    for (int it = 0; it < NUM_ITERS; ++it) {
        const float* act = (it == 0) ? act_in : (const float*)0;
        const float* se  = (it == 0) ? sum_e0 : sum_e1;
        const float* si  = (it == 0) ? sum_i0 : sum_i1;
        const float* h_prev = (it == 0) ? h0 : (out + (size_t)(it - 1) * slice_sz);
        float* h_cur = out + (size_t)it * slice_sz;

        // h_cur = h_prev + e_eff   (excite)
        gemm_fused<<<dim3(NN / 64, QQ / 64, BB), 256, 0, stream>>>(
            adj, h_prev, act, se, h_prev, h_cur, 0);
        // ieff from updated h     (inhibit)
        gemm_fused<<<dim3(NN / 64, QQ / 64, BB), 256, 0, stream>>>(
            adj, h_cur, act, si, (const float*)0, ieff, 1);
        // projection + relu + normalize (np-exact), in place
        project_kernel<<<dim3(NN, BB), 256, 0, stream>>>(h_cur, ieff);
    }
}

// Round 2
// 4133.514 us; speedup vs baseline: 1.3180x; 1.0597x over previous
//
#include <hip/hip_runtime.h>

#define NUM_ITERS 15
#define BB 2
#define NN 2048
#define QQ 256
#define CHUNKS 16          // colsum n-chunks of 128 rows

// ---------------------------------------------------------------------------
// Numerical contract (matches numpy-fp32 golden; verified absmax 0.00195 in
// R8/R9 — LOAD-BEARING, do not relax):
//  - no FMA contraction (pragma clang fp contract(off))
//  - GEMM per output element: single fp32 accumulator, strictly ascending k,
//    round(mul) then round(add), final true division by max(sum,1)
//  - row reductions over q=256: numpy pairwise tree (8-acc blocks of 128,
//    fixed combine), association order replicated exactly
//  - colsum: ascending-n in 16 chunks, combined ascending
// ---------------------------------------------------------------------------

__global__ __launch_bounds__(256) void colsum_part(
    const float* __restrict__ adj, const float* __restrict__ act,
    float* __restrict__ pe0, float* __restrict__ pi0,
    float* __restrict__ pe1, float* __restrict__ pi1)
{
#pragma clang fp contract(off)
    const int b = (int)blockIdx.z;
    const int c = (int)blockIdx.y;
    const int m = (int)blockIdx.x * 256 + (int)threadIdx.x;
    const float* src = adj + (size_t)b * NN * NN;
    const float* ab  = act + (size_t)b * NN;
    float se0 = 0.0f, si0 = 0.0f, se1 = 0.0f, si1 = 0.0f;
    const int n0 = c * (NN / CHUNKS);
    for (int n = n0; n < n0 + NN / CHUNKS; ++n) {
        float x = src[(size_t)n * NN + m];
        float e = (x > 0.5f) ? x : 0.0f;
        float v = 1.0f - x;
        float iv = (v > 0.5f) ? v : 0.0f;
        float av = ab[n];
        se1 = se1 + e;
        si1 = si1 + iv;
        se0 = se0 + e * av;
        si0 = si0 + iv * av;
    }
    size_t o = ((size_t)c * BB + b) * NN + m;
    pe0[o] = se0; pi0[o] = si0; pe1[o] = se1; pi1[o] = si1;
}

__global__ __launch_bounds__(256) void colsum_combine(
    const float* __restrict__ pe0, const float* __restrict__ pi0,
    const float* __restrict__ pe1, const float* __restrict__ pi1,
    float* __restrict__ se0, float* __restrict__ si0,
    float* __restrict__ se1, float* __restrict__ si1)
{
#pragma clang fp contract(off)
    const int i = (int)blockIdx.x * 256 + (int)threadIdx.x;   // 0..BB*NN-1
    float a = 0.0f, bb = 0.0f, cc = 0.0f, dd = 0.0f;
    for (int c = 0; c < CHUNKS; ++c) {
        size_t o = (size_t)c * (BB * NN) + i;
        a  = a  + pe0[o];
        bb = bb + pi0[o];
        cc = cc + pe1[o];
        dd = dd + pi1[o];
    }
    se0[i] = a; si0[i] = bb; se1[i] = cc; si1[i] = dd;
}

// ---------------------------------------------------------------------------
// Fused thresholded GEMM, np-fp32-exact per-element chain:
//   C[m][q] = sum_k (thr(adj[k][m]) * act[k]) * hsrc[k][q]   (ascending k)
//   mode 0: dst = h_old + C/max(sum,1);  mode 1: dst = C/max(sum,1)
//
// v3 (this round): tile M=64 x Q=64, BK=64, 512 threads, 4x2 microtile.
//  - v2 (4x4 microtile, 256 thr) was latency-bound: 1 wave/SIMD (Occupancy
//    11%), VALUBusy 38% — ds_read latency serialized the inner loop.
//  - 512 threads -> 8 waves/block = 2 waves/SIMD (grid stays 256 = 1
//    block/CU): TLP hides LDS latency. LDS/MAC 0.5 -> 0.75 but still
//    VALU-dominated (18 cyc LDS vs 32 cyc VALU per kk per wave).
//  - lane map: tq = tid&31 (float2 q-cols, coalesced stores), tm = tid>>5
//    (4 m-rows, Ws read is a 2-address b128 broadcast per wave).
//  - register prefetch of next K-tile retained from v2.
//  - per-element arithmetic chain (ascending k, mul then add, contract off,
//    true division) is bit-identical to the previous passing kernel.
// ---------------------------------------------------------------------------
__global__ __launch_bounds__(512, 1) void gemm_fused(
    const float* __restrict__ adj,
    const float* __restrict__ hsrc,
    const float* act,
    const float* __restrict__ sums,
    const float* h_old,
    float* __restrict__ dst,
    int mode)
{
#pragma clang fp contract(off)
    __shared__ float4 Ws[64][17];   // 64 k-rows x 16 float4 m-cols (+1 pad)
    __shared__ float4 Hs[64][17];   // 64 k-rows x 16 float4 q-cols (+1 pad)

    const int b  = (int)blockIdx.z;
    const int m0 = (int)blockIdx.x * 64;
    const int q0 = (int)blockIdx.y * 64;
    const int tid = (int)threadIdx.x;
    const int tq  = tid & 31;      // q-group: cols q0 + tq*2 .. +1
    const int tm  = tid >> 5;      // m-group: rows m0 + tm*4 .. +3

    const float* adjb = adj + (size_t)b * NN * NN;
    const float* hb   = hsrc + (size_t)b * NN * QQ;
    const float* ab   = (act != 0) ? (act + (size_t)b * NN) : (const float*)0;

    float acc[4][2];
    #pragma unroll
    for (int i = 0; i < 4; ++i)
        #pragma unroll
        for (int j = 0; j < 2; ++j)
            acc[i][j] = 0.0f;

    float4 wreg[2], hreg[2];

    // issue global loads for K-tile starting at kbase into regs
    auto stage_load = [&](int kbase) {
#pragma clang fp contract(off)
        #pragma unroll
        for (int j = 0; j < 2; ++j) {
            int idx = tid + j * 512;           // 0..1023
            int kk  = idx >> 4;                // 0..63
            int seg = idx & 15;                // 0..15 (float4 col)
            wreg[j] = *(const float4*)(adjb + (size_t)(kbase + kk) * NN + m0 + seg * 4);
            hreg[j] = *(const float4*)(hb   + (size_t)(kbase + kk) * QQ + q0 + seg * 4);
        }
    };

    // threshold + write regs -> LDS (kbase only needed for act indexing)
    auto stage_store = [&](int kbase) {
#pragma clang fp contract(off)
        #pragma unroll
        for (int j = 0; j < 2; ++j) {
            int idx = tid + j * 512;
            int kk  = idx >> 4;
            int seg = idx & 15;
            float4 x = wreg[j];
            float4 w;
            if (mode == 0) {
                w.x = (x.x > 0.5f) ? x.x : 0.0f;
                w.y = (x.y > 0.5f) ? x.y : 0.0f;
                w.z = (x.z > 0.5f) ? x.z : 0.0f;
                w.w = (x.w > 0.5f) ? x.w : 0.0f;
            } else {
                float vx = 1.0f - x.x; w.x = (vx > 0.5f) ? vx : 0.0f;
                float vy = 1.0f - x.y; w.y = (vy > 0.5f) ? vy : 0.0f;
                float vz = 1.0f - x.z; w.z = (vz > 0.5f) ? vz : 0.0f;
                float vw = 1.0f - x.w; w.w = (vw > 0.5f) ? vw : 0.0f;
            }
            if (ab != 0) {
                float av = ab[kbase + kk];
                w.x = w.x * av; w.y = w.y * av; w.z = w.z * av; w.w = w.w * av;
            }
            Ws[kk][seg] = w;
            Hs[kk][seg] = hreg[j];
        }
    };

    // prologue: tile 0 into LDS
    stage_load(0);
    stage_store(0);
    __syncthreads();

    for (int k0 = 0; k0 < NN; k0 += 64) {
        const int knext = k0 + 64;
        if (knext < NN) stage_load(knext);     // overlap with compute below

        #pragma unroll
        for (int kk = 0; kk < 64; ++kk) {
            float4 a4 = Ws[kk][tm];
            float2 b2 = ((const float2*)&Hs[kk][0])[tq];
            float va[4] = {a4.x, a4.y, a4.z, a4.w};
            #pragma unroll
            for (int i = 0; i < 4; ++i) {
                acc[i][0] = acc[i][0] + va[i] * b2.x;
                acc[i][1] = acc[i][1] + va[i] * b2.y;
            }
        }
        __syncthreads();                       // all waves done reading LDS
        if (knext < NN) {
            stage_store(knext);                // implicit vmcnt wait here
            __syncthreads();                   // stores visible before reads
        }
    }

    // epilogue: true division, optional h_old add, float2 stores
    #pragma unroll
    for (int i = 0; i < 4; ++i) {
        int row = m0 + tm * 4 + i;
        float s = sums[b * NN + row];
        if (s < 1.0f) s = 1.0f;
        float v0 = acc[i][0] / s;
        float v1 = acc[i][1] / s;
        size_t g = ((size_t)b * NN + row) * QQ + q0 + tq * 2;
        float2 o;
        if (mode == 0) {
            float2 ho = *(const float2*)(h_old + g);
            o.x = ho.x + v0; o.y = ho.y + v1;
        } else {
            o.x = v0; o.y = v1;
        }
        *(float2*)(dst + g) = o;
    }
}

// ---------------------------------------------------------------------------
// Projection + relu + L2-normalize, np-fp32-exact, in place on h_io.
// Pairwise trees parallelized with IDENTICAL association order.
// Block = one row m (256 threads). Grid (NN, BB).
// ---------------------------------------------------------------------------
__global__ __launch_bounds__(256) void project_kernel(
    float* h_io, const float* __restrict__ ieff)
{
#pragma clang fp contract(off)
    __shared__ float sp[256];
    __shared__ float sq[256];
    __shared__ float rs[32];
    __shared__ float sc[2];
    const int b = (int)blockIdx.y;
    const int m = (int)blockIdx.x;
    const int t = (int)threadIdx.x;

    size_t gi = ((size_t)b * NN + m) * QQ + t;
    float hv = h_io[gi];
    float ie = ieff[gi];

    sp[t] = hv * ie;
    sq[t] = ie * ie;
    __syncthreads();
    if (t < 32) {
        const float* a = (t < 16) ? sp : sq;
        int j = t & 7;
        int base = (t & 8) ? 128 : 0;
        float r = a[base + j];
        for (int i = 8; i < 128; i += 8) r = r + a[base + i + j];
        rs[t] = r;
    }
    __syncthreads();
    if (t == 0) {
        float d0 = ((rs[0] + rs[1]) + (rs[2] + rs[3])) + ((rs[4] + rs[5]) + (rs[6] + rs[7]));
        float d1 = ((rs[8] + rs[9]) + (rs[10] + rs[11])) + ((rs[12] + rs[13]) + (rs[14] + rs[15]));
        float dot = d0 + d1;
        float u0 = ((rs[16] + rs[17]) + (rs[18] + rs[19])) + ((rs[20] + rs[21]) + (rs[22] + rs[23]));
        float u1 = ((rs[24] + rs[25]) + (rs[26] + rs[27])) + ((rs[28] + rs[29]) + (rs[30] + rs[31]));
        float un = u0 + u1;
        sc[0] = dot / (un + 1e-12f);
    }
    __syncthreads();
    float c = sc[0];
    float tmp = c * ie;
    float h2 = hv - tmp;
    float r = (h2 > 0.0f) ? h2 : 0.0f;
    sp[t] = r * r;
    __syncthreads();
    if (t < 16) {
        int j = t & 7;
        int base = (t & 8) ? 128 : 0;
        float rr = sp[base + j];
        for (int i = 8; i < 128; i += 8) rr = rr + sp[base + i + j];
        rs[t] = rr;
    }
    __syncthreads();
    if (t == 0) {
        float n0 = ((rs[0] + rs[1]) + (rs[2] + rs[3])) + ((rs[4] + rs[5]) + (rs[6] + rs[7]));
        float n1 = ((rs[8] + rs[9]) + (rs[10] + rs[11])) + ((rs[12] + rs[13]) + (rs[14] + rs[15]));
        float nn = n0 + n1;
        float den = (float)sqrt((double)nn);
        if (den < 1e-8f) den = 1e-8f;
        sc[1] = den;
    }
    __syncthreads();
    h_io[gi] = r / sc[1];
}

// ---------------------------------------------------------------------------
extern "C" void kernel_launch(void* const* d_in, const int* in_sizes, int n_in,
                              void* d_out, int out_size, void* d_ws, size_t ws_size,
                              hipStream_t stream)
{
    const float* h0     = 0;
    const float* adj    = 0;
    const float* act_in = 0;
    for (int i = 0; i < n_in; ++i) {
        if (in_sizes[i] == BB * NN * QQ)      h0     = (const float*)d_in[i];
        else if (in_sizes[i] == BB * NN * NN) adj    = (const float*)d_in[i];
        else if (in_sizes[i] == BB * NN)      act_in = (const float*)d_in[i];
    }
    float* out = (float*)d_out;

    char* ws = (char*)d_ws;
    size_t off = 0;
    float* ieff = (float*)(ws + off); off += (size_t)BB * NN * QQ * 4;      // 4 MB
    float* pe0 = (float*)(ws + off); off += (size_t)CHUNKS * BB * NN * 4;   // 256 KB
    float* pi0 = (float*)(ws + off); off += (size_t)CHUNKS * BB * NN * 4;
    float* pe1 = (float*)(ws + off); off += (size_t)CHUNKS * BB * NN * 4;
    float* pi1 = (float*)(ws + off); off += (size_t)CHUNKS * BB * NN * 4;
    float* sum_e0 = (float*)(ws + off); off += (size_t)BB * NN * 4;
    float* sum_i0 = (float*)(ws + off); off += (size_t)BB * NN * 4;
    float* sum_e1 = (float*)(ws + off); off += (size_t)BB * NN * 4;
    float* sum_i1 = (float*)(ws + off); off += (size_t)BB * NN * 4;

    const size_t slice_sz = (size_t)BB * NN * QQ;

    colsum_part<<<dim3(NN / 256, CHUNKS, BB), 256, 0, stream>>>(
        adj, act_in, pe0, pi0, pe1, pi1);
    colsum_combine<<<dim3(BB * NN / 256), 256, 0, stream>>>(
        pe0, pi0, pe1, pi1, sum_e0, sum_i0, sum_e1, sum_i1);

    for (int it = 0; it < NUM_ITERS; ++it) {
        const float* act = (it == 0) ? act_in : (const float*)0;
        const float* se  = (it == 0) ? sum_e0 : sum_e1;
        const float* si  = (it == 0) ? sum_i0 : sum_i1;
        const float* h_prev = (it == 0) ? h0 : (out + (size_t)(it - 1) * slice_sz);
        float* h_cur = out + (size_t)it * slice_sz;

        // h_cur = h_prev + e_eff   (excite)
        gemm_fused<<<dim3(NN / 64, QQ / 64, BB), 512, 0, stream>>>(
            adj, h_prev, act, se, h_prev, h_cur, 0);
        // ieff from updated h     (inhibit)
        gemm_fused<<<dim3(NN / 64, QQ / 64, BB), 512, 0, stream>>>(
            adj, h_cur, act, si, (const float*)0, ieff, 1);
        // projection + relu + normalize (np-exact), in place
        project_kernel<<<dim3(NN, BB), 256, 0, stream>>>(h_cur, ieff);
    }
}

// Round 3
// 3862.886 us; speedup vs baseline: 1.4103x; 1.0701x over previous
//
#include <hip/hip_runtime.h>

#define NUM_ITERS 15
#define BB 2
#define NN 2048
#define QQ 256
#define CHUNKS 16          // colsum n-chunks of 128 rows

// ---------------------------------------------------------------------------
// Numerical contract (matches numpy-fp32 golden; verified absmax 0.00195 —
// LOAD-BEARING, do not relax):
//  - no FMA contraction (pragma clang fp contract(off))
//  - GEMM per output element: single fp32 accumulator, strictly ascending k,
//    round(mul) then round(add), final true division by max(sum,1)
//  - row reductions over q=256: numpy pairwise tree (8-acc blocks of 128,
//    fixed combine), association order replicated exactly
//  - colsum: ascending-n in 16 chunks, combined ascending
// ---------------------------------------------------------------------------

__global__ __launch_bounds__(256) void colsum_part(
    const float* __restrict__ adj, const float* __restrict__ act,
    float* __restrict__ pe0, float* __restrict__ pi0,
    float* __restrict__ pe1, float* __restrict__ pi1)
{
#pragma clang fp contract(off)
    const int b = (int)blockIdx.z;
    const int c = (int)blockIdx.y;
    const int m = (int)blockIdx.x * 256 + (int)threadIdx.x;
    const float* src = adj + (size_t)b * NN * NN;
    const float* ab  = act + (size_t)b * NN;
    float se0 = 0.0f, si0 = 0.0f, se1 = 0.0f, si1 = 0.0f;
    const int n0 = c * (NN / CHUNKS);
    for (int n = n0; n < n0 + NN / CHUNKS; ++n) {
        float x = src[(size_t)n * NN + m];
        float e = (x > 0.5f) ? x : 0.0f;
        float v = 1.0f - x;
        float iv = (v > 0.5f) ? v : 0.0f;
        float av = ab[n];
        se1 = se1 + e;
        si1 = si1 + iv;
        se0 = se0 + e * av;
        si0 = si0 + iv * av;
    }
    size_t o = ((size_t)c * BB + b) * NN + m;
    pe0[o] = se0; pi0[o] = si0; pe1[o] = se1; pi1[o] = si1;
}

__global__ __launch_bounds__(256) void colsum_combine(
    const float* __restrict__ pe0, const float* __restrict__ pi0,
    const float* __restrict__ pe1, const float* __restrict__ pi1,
    float* __restrict__ se0, float* __restrict__ si0,
    float* __restrict__ se1, float* __restrict__ si1)
{
#pragma clang fp contract(off)
    const int i = (int)blockIdx.x * 256 + (int)threadIdx.x;   // 0..BB*NN-1
    float a = 0.0f, bb = 0.0f, cc = 0.0f, dd = 0.0f;
    for (int c = 0; c < CHUNKS; ++c) {
        size_t o = (size_t)c * (BB * NN) + i;
        a  = a  + pe0[o];
        bb = bb + pi0[o];
        cc = cc + pe1[o];
        dd = dd + pi1[o];
    }
    se0[i] = a; si0[i] = bb; se1[i] = cc; si1[i] = dd;
}

// ---------------------------------------------------------------------------
// Fused thresholded GEMM, np-fp32-exact per-element chain:
//   C[m][q] = sum_k (thr(adj[k][m]) * act[k]) * hsrc[k][q]   (ascending k)
//   mode 0: dst = h_old + C/max(sum,1);  mode 1: dst = C/max(sum,1)
//
// v4 (this round): 64x64 tile, BK=64, 512 threads, 4x2 microtile, plus:
//  - explicit 2-deep register pipeline in the inner loop (prefetch kk+2's
//    fragments before kk's MACs; static double-buffer indices under full
//    unroll). v3 was LDS-LATENCY-bound: per-kk ds_read latency (~100cy)
//    fully exposed -> VALUBusy 43%, dur 158us. Model matched R0/R1/R2.
//  - LDS double-buffer with ONE barrier per K-tile (stage writes go to the
//    buffer not being read; 68 KB LDS, still 1 block/CU).
//  - __launch_bounds__(512,2): VGPR cap 128 gives regalloc room for the
//    pipeline buffers.
//  - per-element arithmetic chain (ascending k, mul then add, contract off,
//    true division) is bit-identical to the previous passing kernel.
// ---------------------------------------------------------------------------
__global__ __launch_bounds__(512, 2) void gemm_fused(
    const float* __restrict__ adj,
    const float* __restrict__ hsrc,
    const float* act,
    const float* __restrict__ sums,
    const float* h_old,
    float* __restrict__ dst,
    int mode)
{
#pragma clang fp contract(off)
    __shared__ float4 W2[2][64][17];   // [dbuf][k-row][16 float4 m-cols +pad]
    __shared__ float4 H2[2][64][17];

    const int b  = (int)blockIdx.z;
    const int m0 = (int)blockIdx.x * 64;
    const int q0 = (int)blockIdx.y * 64;
    const int tid = (int)threadIdx.x;
    const int tq  = tid & 31;      // q-group: cols q0 + tq*2 .. +1
    const int tm  = tid >> 5;      // m-group: rows m0 + tm*4 .. +3

    const float* adjb = adj + (size_t)b * NN * NN;
    const float* hb   = hsrc + (size_t)b * NN * QQ;
    const float* ab   = (act != 0) ? (act + (size_t)b * NN) : (const float*)0;

    float acc[4][2];
    #pragma unroll
    for (int i = 0; i < 4; ++i)
        #pragma unroll
        for (int j = 0; j < 2; ++j)
            acc[i][j] = 0.0f;

    float4 wreg[2], hreg[2];

    // issue global loads for K-tile starting at kbase into regs
    auto stage_load = [&](int kbase) {
#pragma clang fp contract(off)
        #pragma unroll
        for (int j = 0; j < 2; ++j) {
            int idx = tid + j * 512;           // 0..1023
            int kk  = idx >> 4;                // 0..63
            int seg = idx & 15;                // 0..15 (float4 col)
            wreg[j] = *(const float4*)(adjb + (size_t)(kbase + kk) * NN + m0 + seg * 4);
            hreg[j] = *(const float4*)(hb   + (size_t)(kbase + kk) * QQ + q0 + seg * 4);
        }
    };

    // threshold + write regs -> LDS buffer sbuf (kbase for act indexing)
    auto stage_store = [&](int sbuf, int kbase) {
#pragma clang fp contract(off)
        #pragma unroll
        for (int j = 0; j < 2; ++j) {
            int idx = tid + j * 512;
            int kk  = idx >> 4;
            int seg = idx & 15;
            float4 x = wreg[j];
            float4 w;
            if (mode == 0) {
                w.x = (x.x > 0.5f) ? x.x : 0.0f;
                w.y = (x.y > 0.5f) ? x.y : 0.0f;
                w.z = (x.z > 0.5f) ? x.z : 0.0f;
                w.w = (x.w > 0.5f) ? x.w : 0.0f;
            } else {
                float vx = 1.0f - x.x; w.x = (vx > 0.5f) ? vx : 0.0f;
                float vy = 1.0f - x.y; w.y = (vy > 0.5f) ? vy : 0.0f;
                float vz = 1.0f - x.z; w.z = (vz > 0.5f) ? vz : 0.0f;
                float vw = 1.0f - x.w; w.w = (vw > 0.5f) ? vw : 0.0f;
            }
            if (ab != 0) {
                float av = ab[kbase + kk];
                w.x = w.x * av; w.y = w.y * av; w.z = w.z * av; w.w = w.w * av;
            }
            W2[sbuf][kk][seg] = w;
            H2[sbuf][kk][seg] = hreg[j];
        }
    };

    // compute one K-tile from LDS buffer cbuf, 2-deep register pipeline
    auto compute = [&](int cbuf) {
#pragma clang fp contract(off)
        const float4 (&Ws)[64][17] = W2[cbuf];
        const float4 (&Hs)[64][17] = H2[cbuf];
        float4 a0 = Ws[0][tm];
        float2 p0 = ((const float2*)&Hs[0][0])[tq];
        float4 a1 = Ws[1][tm];
        float2 p1 = ((const float2*)&Hs[1][0])[tq];
        #pragma unroll
        for (int kk = 0; kk < 64; ++kk) {
            float4 a4;
            float2 b2;
            if ((kk & 1) == 0) { a4 = a0; b2 = p0; }
            else               { a4 = a1; b2 = p1; }
            if (kk + 2 < 64) {
                if ((kk & 1) == 0) {
                    a0 = Ws[kk + 2][tm];
                    p0 = ((const float2*)&Hs[kk + 2][0])[tq];
                } else {
                    a1 = Ws[kk + 2][tm];
                    p1 = ((const float2*)&Hs[kk + 2][0])[tq];
                }
            }
            float va[4] = {a4.x, a4.y, a4.z, a4.w};
            #pragma unroll
            for (int i = 0; i < 4; ++i) {
                acc[i][0] = acc[i][0] + va[i] * b2.x;
                acc[i][1] = acc[i][1] + va[i] * b2.y;
            }
        }
    };

    // prologue: tile 0 into LDS buffer 0
    stage_load(0);
    stage_store(0, 0);
    __syncthreads();

    int cur = 0;
    for (int k0 = 0; k0 < NN; k0 += 64) {
        const int knext = k0 + 64;
        if (knext < NN) stage_load(knext);     // VMEM issue, hidden by compute
        compute(cur);
        if (knext < NN) {
            stage_store(cur ^ 1, knext);       // writes the OTHER buffer
            __syncthreads();                   // one barrier per tile
            cur ^= 1;
        }
    }

    // epilogue: true division, optional h_old add, float2 stores
    #pragma unroll
    for (int i = 0; i < 4; ++i) {
        int row = m0 + tm * 4 + i;
        float s = sums[b * NN + row];
        if (s < 1.0f) s = 1.0f;
        float v0 = acc[i][0] / s;
        float v1 = acc[i][1] / s;
        size_t g = ((size_t)b * NN + row) * QQ + q0 + tq * 2;
        float2 o;
        if (mode == 0) {
            float2 ho = *(const float2*)(h_old + g);
            o.x = ho.x + v0; o.y = ho.y + v1;
        } else {
            o.x = v0; o.y = v1;
        }
        *(float2*)(dst + g) = o;
    }
}

// ---------------------------------------------------------------------------
// Projection + relu + L2-normalize, np-fp32-exact, in place on h_io.
// Pairwise trees parallelized with IDENTICAL association order.
// Block = one row m (256 threads). Grid (NN, BB).
// ---------------------------------------------------------------------------
__global__ __launch_bounds__(256) void project_kernel(
    float* h_io, const float* __restrict__ ieff)
{
#pragma clang fp contract(off)
    __shared__ float sp[256];
    __shared__ float sq[256];
    __shared__ float rs[32];
    __shared__ float sc[2];
    const int b = (int)blockIdx.y;
    const int m = (int)blockIdx.x;
    const int t = (int)threadIdx.x;

    size_t gi = ((size_t)b * NN + m) * QQ + t;
    float hv = h_io[gi];
    float ie = ieff[gi];

    sp[t] = hv * ie;
    sq[t] = ie * ie;
    __syncthreads();
    if (t < 32) {
        const float* a = (t < 16) ? sp : sq;
        int j = t & 7;
        int base = (t & 8) ? 128 : 0;
        float r = a[base + j];
        for (int i = 8; i < 128; i += 8) r = r + a[base + i + j];
        rs[t] = r;
    }
    __syncthreads();
    if (t == 0) {
        float d0 = ((rs[0] + rs[1]) + (rs[2] + rs[3])) + ((rs[4] + rs[5]) + (rs[6] + rs[7]));
        float d1 = ((rs[8] + rs[9]) + (rs[10] + rs[11])) + ((rs[12] + rs[13]) + (rs[14] + rs[15]));
        float dot = d0 + d1;
        float u0 = ((rs[16] + rs[17]) + (rs[18] + rs[19])) + ((rs[20] + rs[21]) + (rs[22] + rs[23]));
        float u1 = ((rs[24] + rs[25]) + (rs[26] + rs[27])) + ((rs[28] + rs[29]) + (rs[30] + rs[31]));
        float un = u0 + u1;
        sc[0] = dot / (un + 1e-12f);
    }
    __syncthreads();
    float c = sc[0];
    float tmp = c * ie;
    float h2 = hv - tmp;
    float r = (h2 > 0.0f) ? h2 : 0.0f;
    sp[t] = r * r;
    __syncthreads();
    if (t < 16) {
        int j = t & 7;
        int base = (t & 8) ? 128 : 0;
        float rr = sp[base + j];
        for (int i = 8; i < 128; i += 8) rr = rr + sp[base + i + j];
        rs[t] = rr;
    }
    __syncthreads();
    if (t == 0) {
        float n0 = ((rs[0] + rs[1]) + (rs[2] + rs[3])) + ((rs[4] + rs[5]) + (rs[6] + rs[7]));
        float n1 = ((rs[8] + rs[9]) + (rs[10] + rs[11])) + ((rs[12] + rs[13]) + (rs[14] + rs[15]));
        float nn = n0 + n1;
        float den = (float)sqrt((double)nn);
        if (den < 1e-8f) den = 1e-8f;
        sc[1] = den;
    }
    __syncthreads();
    h_io[gi] = r / sc[1];
}

// ---------------------------------------------------------------------------
extern "C" void kernel_launch(void* const* d_in, const int* in_sizes, int n_in,
                              void* d_out, int out_size, void* d_ws, size_t ws_size,
                              hipStream_t stream)
{
    const float* h0     = 0;
    const float* adj    = 0;
    const float* act_in = 0;
    for (int i = 0; i < n_in; ++i) {
        if (in_sizes[i] == BB * NN * QQ)      h0     = (const float*)d_in[i];
        else if (in_sizes[i] == BB * NN * NN) adj    = (const float*)d_in[i];
        else if (in_sizes[i] == BB * NN)      act_in = (const float*)d_in[i];
    }
    float* out = (float*)d_out;

    char* ws = (char*)d_ws;
    size_t off = 0;
    float* ieff = (float*)(ws + off); off += (size_t)BB * NN * QQ * 4;      // 4 MB
    float* pe0 = (float*)(ws + off); off += (size_t)CHUNKS * BB * NN * 4;   // 256 KB
    float* pi0 = (float*)(ws + off); off += (size_t)CHUNKS * BB * NN * 4;
    float* pe1 = (float*)(ws + off); off += (size_t)CHUNKS * BB * NN * 4;
    float* pi1 = (float*)(ws + off); off += (size_t)CHUNKS * BB * NN * 4;
    float* sum_e0 = (float*)(ws + off); off += (size_t)BB * NN * 4;
    float* sum_i0 = (float*)(ws + off); off += (size_t)BB * NN * 4;
    float* sum_e1 = (float*)(ws + off); off += (size_t)BB * NN * 4;
    float* sum_i1 = (float*)(ws + off); off += (size_t)BB * NN * 4;

    const size_t slice_sz = (size_t)BB * NN * QQ;

    colsum_part<<<dim3(NN / 256, CHUNKS, BB), 256, 0, stream>>>(
        adj, act_in, pe0, pi0, pe1, pi1);
    colsum_combine<<<dim3(BB * NN / 256), 256, 0, stream>>>(
        pe0, pi0, pe1, pi1, sum_e0, sum_i0, sum_e1, sum_i1);

    for (int it = 0; it < NUM_ITERS; ++it) {
        const float* act = (it == 0) ? act_in : (const float*)0;
        const float* se  = (it == 0) ? sum_e0 : sum_e1;
        const float* si  = (it == 0) ? sum_i0 : sum_i1;
        const float* h_prev = (it == 0) ? h0 : (out + (size_t)(it - 1) * slice_sz);
        float* h_cur = out + (size_t)it * slice_sz;

        // h_cur = h_prev + e_eff   (excite)
        gemm_fused<<<dim3(NN / 64, QQ / 64, BB), 512, 0, stream>>>(
            adj, h_prev, act, se, h_prev, h_cur, 0);
        // ieff from updated h     (inhibit)
        gemm_fused<<<dim3(NN / 64, QQ / 64, BB), 512, 0, stream>>>(
            adj, h_cur, act, si, (const float*)0, ieff, 1);
        // projection + relu + normalize (np-exact), in place
        project_kernel<<<dim3(NN, BB), 256, 0, stream>>>(h_cur, ieff);
    }
}